// Round 1
// baseline (516.144 us; speedup 1.0000x reference)
//
#include <hip/hip_runtime.h>

#define D_ORIENT 12
#define HW 16384                    // 128*128
#define SLICE (D_ORIENT * HW)       // 196608 elements per (b,c)
#define NTHREADS 1024

// One block per (b,c). Phase 1: strided float4 scan + argmax reduction
// (first-occurrence tie-break = min flat index, matching jnp.argmax).
// Phase 2: cooperative copy of the winning HxW slice.
__global__ __launch_bounds__(NTHREADS) void opool_kernel(const float* __restrict__ x,
                                                         float* __restrict__ out) {
    const int bc = blockIdx.x;
    const float* __restrict__ src = x + (size_t)bc * SLICE;
    const int tid = threadIdx.x;

    float best = -__builtin_inff();
    int bestIdx = 0;

    // 196608/4 = 49152 float4; /1024 threads = 48 iterations, fully coalesced.
    const float4* __restrict__ src4 = (const float4*)src;
    #pragma unroll 4
    for (int i = tid; i < SLICE / 4; i += NTHREADS) {
        float4 v = src4[i];
        int base = i * 4;
        // per-thread indices strictly increase, so '>' preserves first-occurrence
        if (v.x > best) { best = v.x; bestIdx = base; }
        if (v.y > best) { best = v.y; bestIdx = base + 1; }
        if (v.z > best) { best = v.z; bestIdx = base + 2; }
        if (v.w > best) { best = v.w; bestIdx = base + 3; }
    }

    // wave-64 shuffle reduction with min-index tie-break
    for (int off = 32; off >= 1; off >>= 1) {
        float ov = __shfl_down(best, off, 64);
        int   oi = __shfl_down(bestIdx, off, 64);
        if (ov > best || (ov == best && oi < bestIdx)) { best = ov; bestIdx = oi; }
    }

    __shared__ float s_val[NTHREADS / 64];
    __shared__ int   s_idx[NTHREADS / 64];
    __shared__ int   s_d;
    const int wave = tid >> 6;
    const int lane = tid & 63;
    if (lane == 0) { s_val[wave] = best; s_idx[wave] = bestIdx; }
    __syncthreads();
    if (tid == 0) {
        float bv = s_val[0];
        int   bi = s_idx[0];
        #pragma unroll
        for (int w = 1; w < NTHREADS / 64; ++w) {
            float v = s_val[w];
            int   i2 = s_idx[w];
            if (v > bv || (v == bv && i2 < bi)) { bv = v; bi = i2; }
        }
        s_d = bi / HW;   // winning orientation
    }
    __syncthreads();

    // Phase 2: copy winning slice (16384 floats = 4096 float4 / 1024 thr = 4 iters)
    const float4* __restrict__ win = (const float4*)(src + (size_t)s_d * HW);
    float4* __restrict__ dst = (float4*)(out + (size_t)bc * HW);
    #pragma unroll
    for (int i = tid; i < HW / 4; i += NTHREADS) {
        dst[i] = win[i];
    }
}

extern "C" void kernel_launch(void* const* d_in, const int* in_sizes, int n_in,
                              void* d_out, int out_size, void* d_ws, size_t ws_size,
                              hipStream_t stream) {
    const float* x = (const float*)d_in[0];
    float* out = (float*)d_out;
    const int n_bc = out_size / HW;   // B*C = 512
    opool_kernel<<<n_bc, NTHREADS, 0, stream>>>(x, out);
}